// Round 6
// baseline (718.710 us; speedup 1.0000x reference)
//
#include <hip/hip_runtime.h>
#include <cstdint>

#define CIN    512
#define COUT   32
#define IMH    56
#define IMW    56
#define NB     32
#define CHUNKS 16
#define XSTR   40          // shorts per pixel (32 k + 8 pad) = 80 B; 2-way-max banks
#define NTH    256
#define YT     28          // 2-row output tiles
#define SLOTS  896         // 4 rows x 14 xg x 16 c2
#define SPT    4           // ceil(896/256)
#define BUFS   (4 * 58 * XSTR)   // 9280 shorts = 18560 B per LDS buffer

typedef __attribute__((ext_vector_type(8))) short v8s;   // 8 bf16 = 4 VGPRs
typedef __attribute__((ext_vector_type(4))) float v4f;

__device__ __forceinline__ unsigned short f2bf(float f) {
    unsigned u = __builtin_bit_cast(unsigned, f);
    u += 0x7FFFu + ((u >> 16) & 1u);          // round-to-nearest-even
    return (unsigned short)(u >> 16);
}

// ---------------------------------------------------------------------------
// Weight transform (fp32 OIHW -> bf16 MFMA A-frag order) + BN const table.
// w2[(((gc*9+tap)*2+mt)*64+lane)*8+j] = W[m=mt*16+(lane&15)][k=gc*32+(lane>>4)*8+j][tap]
// bq[gc*16+c2] = {scale0, shift0, scale1, shift1} for channels gc*32+2*c2, +1
// ---------------------------------------------------------------------------
__global__ void wtransform(const float* __restrict__ cw,
                           const float* __restrict__ bn_w, const float* __restrict__ bn_b,
                           const float* __restrict__ rm,   const float* __restrict__ rv,
                           unsigned short* __restrict__ w2, float4* __restrict__ bq) {
    int idx = blockIdx.x * blockDim.x + threadIdx.x;
    if (idx < 256) {
        int c = idx * 2;
        float s0 = bn_w[c]     * rsqrtf(rv[c]     + 1e-5f);
        float s1 = bn_w[c + 1] * rsqrtf(rv[c + 1] + 1e-5f);
        bq[idx] = make_float4(s0, bn_b[c] - rm[c] * s0, s1, bn_b[c + 1] - rm[c + 1] * s1);
    }
    if (idx >= CHUNKS * 9 * 2 * 64 * 8) return;
    int j    = idx & 7;
    int lane = (idx >> 3) & 63;
    int mt   = (idx >> 9) & 1;
    int tmp  = idx >> 10;
    int tap  = tmp % 9;
    int gc   = tmp / 9;
    int m = mt * 16 + (lane & 15);
    int k = gc * 32 + (lane >> 4) * 8 + j;
    w2[idx] = f2bf(cw[((size_t)m * CIN + k) * 9 + tap]);
}

// ---------------------------------------------------------------------------
// One-pass fused BN+ReLU+3x3 conv, tap-decomposed MFMA implicit GEMM.
// 896 blocks (yt=28 x n=32), 3 blocks/CU -> ~12 waves/CU for HBM MLP.
// Per chunk: weights(gc) -> prefetch inputs(gc+1) -> pack(gc) -> barrier
// -> MFMA(gc). Input regs + LDS both double-buffered; one barrier/chunk.
// ---------------------------------------------------------------------------
struct SlotTab {
    int lbase[SPT];
    int gofs[SPT];
    int actm;            // bit j = slot j active (in range & valid row)
};

__device__ __forceinline__ void load_inputs(const float* __restrict__ p0,
                                            const SlotTab& st,
                                            float4 (&va)[SPT], float4 (&vb)[SPT]) {
    #pragma unroll
    for (int j = 0; j < SPT; ++j) {
        if (st.actm & (1 << j)) {
            const float* p = p0 + st.gofs[j];
            va[j] = *(const float4*)p;
            vb[j] = *(const float4*)(p + 3136);
        }
    }
}

__device__ __forceinline__ void pack_chunk(unsigned short* __restrict__ bp,
                                           const SlotTab& st, float4 bn,
                                           const float4 (&va)[SPT], const float4 (&vb)[SPT]) {
    #pragma unroll
    for (int j = 0; j < SPT; ++j) {
        if (st.actm & (1 << j)) {
            float a0 = fmaxf(fmaf(va[j].x, bn.x, bn.y), 0.f);
            float a1 = fmaxf(fmaf(va[j].y, bn.x, bn.y), 0.f);
            float a2 = fmaxf(fmaf(va[j].z, bn.x, bn.y), 0.f);
            float a3 = fmaxf(fmaf(va[j].w, bn.x, bn.y), 0.f);
            float b0 = fmaxf(fmaf(vb[j].x, bn.z, bn.w), 0.f);
            float b1 = fmaxf(fmaf(vb[j].y, bn.z, bn.w), 0.f);
            float b2 = fmaxf(fmaf(vb[j].z, bn.z, bn.w), 0.f);
            float b3 = fmaxf(fmaf(vb[j].w, bn.z, bn.w), 0.f);
            unsigned u0 = (unsigned)f2bf(a0) | ((unsigned)f2bf(b0) << 16);
            unsigned u1 = (unsigned)f2bf(a1) | ((unsigned)f2bf(b1) << 16);
            unsigned u2 = (unsigned)f2bf(a2) | ((unsigned)f2bf(b2) << 16);
            unsigned u3 = (unsigned)f2bf(a3) | ((unsigned)f2bf(b3) << 16);
            int base = st.lbase[j];
            *(unsigned*)&bp[base]            = u0;
            *(unsigned*)&bp[base + XSTR]     = u1;
            *(unsigned*)&bp[base + 2 * XSTR] = u2;
            *(unsigned*)&bp[base + 3 * XSTR] = u3;
        }
    }
}

__global__ __launch_bounds__(NTH, 3)
void conv_mfma(const float* __restrict__ x,
               const unsigned short* __restrict__ w2,
               const float4* __restrict__ bq,
               float* __restrict__ out)
{
    __shared__ __align__(16) unsigned short s_x[2][BUFS];   // 37120 B

    const int tid  = threadIdx.x;
    const int lane = tid & 63;
    const int wv   = tid >> 6;
    const int yt   = blockIdx.x;        // 0..27
    const int n    = blockIdx.y;        // 0..31
    const int y0   = yt * 2;
    const int c2   = tid & 15;

    // --- slot tables: slot = tid + j*256 -> (c2, xg, r) ---
    SlotTab st;
    st.actm = 0;
    #pragma unroll
    for (int j = 0; j < SPT; ++j) {
        int slot = tid + j * NTH;
        bool inr = (slot < SLOTS);
        int rest = slot >> 4;            // 0..63
        int xg = rest % 14;
        int r  = rest / 14;              // 0..3 (garbage for tail -> inr false)
        int iy = y0 - 1 + r;
        bool v = inr && (iy >= 0) && (iy < IMH);
        if (v) st.actm |= (1 << j);
        st.lbase[j] = (r * 58 + xg * 4 + 1) * XSTR + c2 * 2;
        st.gofs[j]  = c2 * 2 * 3136 + (v ? iy : 0) * 56 + xg * 4;
    }

    // --- zero halo cols (px arr 0,57) in both buffers ---
    for (int i = tid; i < 2 * 4 * 2 * 20; i += NTH) {
        int kq = i % 20;
        int t  = i / 20;                 // 0..15: buf(2) x r(4) x side(2)
        int side = t & 1;
        int r  = (t >> 1) & 3;
        int b  = t >> 3;
        *(unsigned*)&s_x[b][(r * 58 + (side ? 57 : 0)) * XSTR + kq * 2] = 0u;
    }
    // --- zero full invalid row (top/bottom tiles), both buffers ---
    if (y0 == 0 || y0 == 2 * (YT - 1)) {
        int r = (y0 == 0) ? 0 : 3;
        for (int i = tid; i < 2 * 58 * 20; i += NTH) {
            int b = i >= 58 * 20;
            int q = i - b * 58 * 20;
            *(unsigned*)&s_x[b][r * 58 * XSTR + q * 2] = 0u;
        }
    }

    // --- B-fragment bases: wave wv owns tiles {2wv, 2wv+1}; wv==3 only {6} ---
    const int ntile = (wv == 3) ? 1 : 2;
    int b_base[2];
    v4f acc[2][2];
    const v4f zero4 = {0.f, 0.f, 0.f, 0.f};
    #pragma unroll
    for (int i = 0; i < 2; ++i) {
        int t  = (wv == 3) ? 6 : (2 * wv + i);
        int p  = t * 16 + (lane & 15);   // 0..111
        int py = p / 56, px = p % 56;
        b_base[i] = (py * 58 + px) * XSTR + (lane >> 4) * 8;
        acc[i][0] = zero4;
        acc[i][1] = zero4;
    }

    const float* xn = x + (size_t)n * CIN * 3136;

    // --- prologue: inputs for chunk 0 into set A ---
    float4 vaA[SPT], vbA[SPT], vaB[SPT], vbB[SPT];
    load_inputs(xn, st, vaA, vbA);

    #define CHUNK_STEP(GC, VAC, VBC, VAN, VBN)                                  \
    {                                                                           \
        const int gc = (GC);                                                    \
        v8s aw0[9], aw1[9];                                                     \
        const v8s* wpv = (const v8s*)(w2 + (size_t)gc * 9216);                  \
        _Pragma("unroll")                                                       \
        for (int t = 0; t < 9; ++t) {                                           \
            aw0[t] = wpv[t * 128 + lane];                                       \
            aw1[t] = wpv[t * 128 + 64 + lane];                                  \
        }                                                                       \
        if (gc < CHUNKS - 1)                                                    \
            load_inputs(xn + (size_t)(gc + 1) * 32 * 3136, st, VAN, VBN);       \
        float4 bn = bq[gc * 16 + c2];                                           \
        unsigned short* bp = &s_x[gc & 1][0];                                   \
        pack_chunk(bp, st, bn, VAC, VBC);                                       \
        __syncthreads();                                                        \
        _Pragma("unroll")                                                       \
        for (int tap = 0; tap < 9; ++tap) {                                     \
            const int toff = ((tap / 3) * 58 + (tap % 3)) * XSTR;               \
            _Pragma("unroll")                                                   \
            for (int i = 0; i < 2; ++i) {                                       \
                if (i < ntile) {                                                \
                    v8s b = *(const v8s*)&bp[b_base[i] + toff];                 \
                    acc[i][0] = __builtin_amdgcn_mfma_f32_16x16x32_bf16(        \
                        aw0[tap], b, acc[i][0], 0, 0, 0);                       \
                    acc[i][1] = __builtin_amdgcn_mfma_f32_16x16x32_bf16(        \
                        aw1[tap], b, acc[i][1], 0, 0, 0);                       \
                }                                                               \
            }                                                                   \
        }                                                                       \
    }

    for (int gp = 0; gp < CHUNKS / 2; ++gp) {
        CHUNK_STEP(2 * gp,     vaA, vbA, vaB, vbB);
        CHUNK_STEP(2 * gp + 1, vaB, vbB, vaA, vbA);
    }
    #undef CHUNK_STEP

    // --- epilogue: direct stores ---
    const int prow = (lane >> 4) * 4;
    #pragma unroll
    for (int i = 0; i < 2; ++i) {
        if (i >= ntile) break;
        int t  = (wv == 3) ? 6 : (2 * wv + i);
        int p  = t * 16 + (lane & 15);
        int py = p / 56, px = p % 56;
        size_t o0 = (size_t)n * COUT * 3136 + (size_t)(y0 + py) * 56 + px;
        #pragma unroll
        for (int mt = 0; mt < 2; ++mt) {
            #pragma unroll
            for (int r = 0; r < 4; ++r) {
                int cout = mt * 16 + prow + r;
                out[o0 + (size_t)cout * 3136] = acc[i][mt][r];
            }
        }
    }
}

extern "C" void kernel_launch(void* const* d_in, const int* in_sizes, int n_in,
                              void* d_out, int out_size, void* d_ws, size_t ws_size,
                              hipStream_t stream) {
    const float* x      = (const float*)d_in[0];
    const float* bn_w   = (const float*)d_in[2];
    const float* bn_b   = (const float*)d_in[3];
    const float* r_mean = (const float*)d_in[4];
    const float* r_var  = (const float*)d_in[5];
    const float* cw     = (const float*)d_in[6];
    float* out = (float*)d_out;

    unsigned short* w2 = (unsigned short*)d_ws;                  // 294912 B
    float4* bq = (float4*)((char*)d_ws + 294912);                // 4096 B

    wtransform<<<dim3(576), dim3(256), 0, stream>>>(cw, bn_w, bn_b, r_mean, r_var, w2, bq);

    conv_mfma<<<dim3(YT, NB), dim3(NTH), 0, stream>>>(x, w2, bq, out);
}

// Round 7
// 637.393 us; speedup vs baseline: 1.1276x; 1.1276x over previous
//
#include <hip/hip_runtime.h>
#include <cstdint>

#define CIN    512
#define COUT   32
#define IMH    56
#define IMW    56
#define NB     32
#define CHUNKS 16
#define XSTR   40          // shorts per pixel (32 k + 8 pad) = 80 B
#define NTH    256
#define YT     28          // 2-row output tiles
#define SLOTS  896         // 4 rows x 14 xg x 16 c2
#define SPT    4           // ceil(896/256)
#define BUFS   (4 * 58 * XSTR)   // 9280 shorts = 18560 B per LDS buffer

typedef __attribute__((ext_vector_type(8))) short v8s;   // 8 bf16 = 4 VGPRs
typedef __attribute__((ext_vector_type(4))) float v4f;

__device__ __forceinline__ unsigned short f2bf(float f) {
    unsigned u = __builtin_bit_cast(unsigned, f);
    u += 0x7FFFu + ((u >> 16) & 1u);          // round-to-nearest-even
    return (unsigned short)(u >> 16);
}

// ---------------------------------------------------------------------------
// Weight transform (fp32 OIHW -> bf16 MFMA A-frag order) + BN const table.
// w2[(((gc*9+tap)*2+mt)*64+lane)*8+j] = W[m=mt*16+(lane&15)][k=gc*32+(lane>>4)*8+j][tap]
// bq[gc*16+c2] = {scale0, shift0, scale1, shift1} for channels gc*32+2*c2, +1
// ---------------------------------------------------------------------------
__global__ void wtransform(const float* __restrict__ cw,
                           const float* __restrict__ bn_w, const float* __restrict__ bn_b,
                           const float* __restrict__ rm,   const float* __restrict__ rv,
                           unsigned short* __restrict__ w2, float4* __restrict__ bq) {
    int idx = blockIdx.x * blockDim.x + threadIdx.x;
    if (idx < 256) {
        int c = idx * 2;
        float s0 = bn_w[c]     * rsqrtf(rv[c]     + 1e-5f);
        float s1 = bn_w[c + 1] * rsqrtf(rv[c + 1] + 1e-5f);
        bq[idx] = make_float4(s0, bn_b[c] - rm[c] * s0, s1, bn_b[c + 1] - rm[c + 1] * s1);
    }
    if (idx >= CHUNKS * 9 * 2 * 64 * 8) return;
    int j    = idx & 7;
    int lane = (idx >> 3) & 63;
    int mt   = (idx >> 9) & 1;
    int tmp  = idx >> 10;
    int tap  = tmp % 9;
    int gc   = tmp / 9;
    int m = mt * 16 + (lane & 15);
    int k = gc * 32 + (lane >> 4) * 8 + j;
    w2[idx] = f2bf(cw[((size_t)m * CIN + k) * 9 + tap]);
}

// ---------------------------------------------------------------------------
// One-pass fused BN+ReLU+3x3 conv, tap-decomposed MFMA implicit GEMM.
// 896 blocks (yt=28 x n=32). Register budget tuned for 3 blocks/CU
// (~160 VGPR <= 168 cap): single input reg set, no weight dbuf, no spill.
// TLP (12 waves/CU) hides the per-chunk barrier drain.
// ---------------------------------------------------------------------------
struct SlotTab {
    int lbase[SPT];
    int gofs[SPT];
    int actm;            // bit j = slot j active (in range & valid row)
};

__device__ __forceinline__ void load_inputs(const float* __restrict__ p0,
                                            const SlotTab& st,
                                            float4 (&va)[SPT], float4 (&vb)[SPT]) {
    #pragma unroll
    for (int j = 0; j < SPT; ++j) {
        if (st.actm & (1 << j)) {
            const float* p = p0 + st.gofs[j];
            va[j] = *(const float4*)p;
            vb[j] = *(const float4*)(p + 3136);
        }
    }
}

__device__ __forceinline__ void pack_chunk(unsigned short* __restrict__ bp,
                                           const SlotTab& st, float4 bn,
                                           const float4 (&va)[SPT], const float4 (&vb)[SPT]) {
    #pragma unroll
    for (int j = 0; j < SPT; ++j) {
        if (st.actm & (1 << j)) {
            float a0 = fmaxf(fmaf(va[j].x, bn.x, bn.y), 0.f);
            float a1 = fmaxf(fmaf(va[j].y, bn.x, bn.y), 0.f);
            float a2 = fmaxf(fmaf(va[j].z, bn.x, bn.y), 0.f);
            float a3 = fmaxf(fmaf(va[j].w, bn.x, bn.y), 0.f);
            float b0 = fmaxf(fmaf(vb[j].x, bn.z, bn.w), 0.f);
            float b1 = fmaxf(fmaf(vb[j].y, bn.z, bn.w), 0.f);
            float b2 = fmaxf(fmaf(vb[j].z, bn.z, bn.w), 0.f);
            float b3 = fmaxf(fmaf(vb[j].w, bn.z, bn.w), 0.f);
            unsigned u0 = (unsigned)f2bf(a0) | ((unsigned)f2bf(b0) << 16);
            unsigned u1 = (unsigned)f2bf(a1) | ((unsigned)f2bf(b1) << 16);
            unsigned u2 = (unsigned)f2bf(a2) | ((unsigned)f2bf(b2) << 16);
            unsigned u3 = (unsigned)f2bf(a3) | ((unsigned)f2bf(b3) << 16);
            int base = st.lbase[j];
            *(unsigned*)&bp[base]            = u0;
            *(unsigned*)&bp[base + XSTR]     = u1;
            *(unsigned*)&bp[base + 2 * XSTR] = u2;
            *(unsigned*)&bp[base + 3 * XSTR] = u3;
        }
    }
}

__global__ __launch_bounds__(NTH, 3)
void conv_mfma(const float* __restrict__ x,
               const unsigned short* __restrict__ w2,
               const float4* __restrict__ bq,
               float* __restrict__ out)
{
    __shared__ __align__(16) unsigned short s_x[2][BUFS];   // 37120 B

    const int tid  = threadIdx.x;
    const int lane = tid & 63;
    const int wv   = tid >> 6;
    const int yt   = blockIdx.x;        // 0..27
    const int n    = blockIdx.y;        // 0..31
    const int y0   = yt * 2;
    const int c2   = tid & 15;

    // --- slot tables: slot = tid + j*256 -> (c2, xg, r) ---
    SlotTab st;
    st.actm = 0;
    #pragma unroll
    for (int j = 0; j < SPT; ++j) {
        int slot = tid + j * NTH;
        bool inr = (slot < SLOTS);
        int rest = slot >> 4;            // 0..63
        int xg = rest % 14;
        int r  = rest / 14;              // 0..3
        int iy = y0 - 1 + r;
        bool v = inr && (iy >= 0) && (iy < IMH);
        if (v) st.actm |= (1 << j);
        st.lbase[j] = (r * 58 + xg * 4 + 1) * XSTR + c2 * 2;
        st.gofs[j]  = c2 * 2 * 3136 + (v ? iy : 0) * 56 + xg * 4;
    }

    // --- zero halo cols (px 0,57) in both buffers ---
    for (int i = tid; i < 2 * 4 * 2 * 20; i += NTH) {
        int kq = i % 20;
        int t  = i / 20;                 // buf(2) x r(4) x side(2)
        int side = t & 1;
        int r  = (t >> 1) & 3;
        int b  = t >> 3;
        *(unsigned*)&s_x[b][(r * 58 + (side ? 57 : 0)) * XSTR + kq * 2] = 0u;
    }
    // --- zero full invalid row (top/bottom tiles), both buffers ---
    if (y0 == 0 || y0 == 2 * (YT - 1)) {
        int r = (y0 == 0) ? 0 : 3;
        for (int i = tid; i < 2 * 58 * 20; i += NTH) {
            int b = i >= 58 * 20;
            int q = i - b * 58 * 20;
            *(unsigned*)&s_x[b][r * 58 * XSTR + q * 2] = 0u;
        }
    }

    // --- B-fragment bases: wave wv owns tiles {2wv, 2wv+1}; wv==3 only {6} ---
    const int ntile = (wv == 3) ? 1 : 2;
    int b_base[2];
    v4f acc[2][2];
    const v4f zero4 = {0.f, 0.f, 0.f, 0.f};
    #pragma unroll
    for (int i = 0; i < 2; ++i) {
        int t  = (wv == 3) ? 6 : (2 * wv + i);
        int p  = t * 16 + (lane & 15);   // 0..111
        int py = p / 56, px = p % 56;
        b_base[i] = (py * 58 + px) * XSTR + (lane >> 4) * 8;
        acc[i][0] = zero4;
        acc[i][1] = zero4;
    }

    const float* xn = x + (size_t)n * CIN * 3136;

    // --- prologue: inputs for chunk 0 (single register set) ---
    float4 va[SPT], vb[SPT];
    load_inputs(xn, st, va, vb);

    for (int gc = 0; gc < CHUNKS; ++gc) {
        // weights for chunk gc from L2 (issued early; drained at the barrier)
        v8s aw0[9], aw1[9];
        const v8s* wpv = (const v8s*)(w2 + (size_t)gc * 9216);
        #pragma unroll
        for (int t = 0; t < 9; ++t) {
            aw0[t] = wpv[t * 128 + lane];
            aw1[t] = wpv[t * 128 + 64 + lane];
        }

        // pack chunk gc (waits this chunk's input regs only)
        float4 bn = bq[gc * 16 + c2];
        unsigned short* bp = &s_x[gc & 1][0];
        pack_chunk(bp, st, bn, va, vb);

        // issue next chunk's inputs into the now-free register set
        if (gc < CHUNKS - 1)
            load_inputs(xn + (size_t)(gc + 1) * 32 * 3136, st, va, vb);

        __syncthreads();    // drains vmem (incl. next inputs) + makes LDS visible

        // MFMA chunk gc
        #pragma unroll
        for (int tap = 0; tap < 9; ++tap) {
            const int toff = ((tap / 3) * 58 + (tap % 3)) * XSTR;
            #pragma unroll
            for (int i = 0; i < 2; ++i) {
                if (i < ntile) {
                    v8s b = *(const v8s*)&bp[b_base[i] + toff];
                    acc[i][0] = __builtin_amdgcn_mfma_f32_16x16x32_bf16(aw0[tap], b, acc[i][0], 0, 0, 0);
                    acc[i][1] = __builtin_amdgcn_mfma_f32_16x16x32_bf16(aw1[tap], b, acc[i][1], 0, 0, 0);
                }
            }
        }
        __syncthreads();    // WAR: all waves done reading buffer gc&1
    }

    // --- epilogue: direct stores ---
    const int prow = (lane >> 4) * 4;
    #pragma unroll
    for (int i = 0; i < 2; ++i) {
        if (i >= ntile) break;
        int t  = (wv == 3) ? 6 : (2 * wv + i);
        int p  = t * 16 + (lane & 15);
        int py = p / 56, px = p % 56;
        size_t o0 = (size_t)n * COUT * 3136 + (size_t)(y0 + py) * 56 + px;
        #pragma unroll
        for (int mt = 0; mt < 2; ++mt) {
            #pragma unroll
            for (int r = 0; r < 4; ++r) {
                int cout = mt * 16 + prow + r;
                out[o0 + (size_t)cout * 3136] = acc[i][mt][r];
            }
        }
    }
}

extern "C" void kernel_launch(void* const* d_in, const int* in_sizes, int n_in,
                              void* d_out, int out_size, void* d_ws, size_t ws_size,
                              hipStream_t stream) {
    const float* x      = (const float*)d_in[0];
    const float* bn_w   = (const float*)d_in[2];
    const float* bn_b   = (const float*)d_in[3];
    const float* r_mean = (const float*)d_in[4];
    const float* r_var  = (const float*)d_in[5];
    const float* cw     = (const float*)d_in[6];
    float* out = (float*)d_out;

    unsigned short* w2 = (unsigned short*)d_ws;                  // 294912 B
    float4* bq = (float4*)((char*)d_ws + 294912);                // 4096 B

    wtransform<<<dim3(576), dim3(256), 0, stream>>>(cw, bn_w, bn_b, r_mean, r_var, w2, bq);

    conv_mfma<<<dim3(YT, NB), dim3(NTH), 0, stream>>>(x, w2, bq, out);
}

// Round 8
// 614.318 us; speedup vs baseline: 1.1699x; 1.0376x over previous
//
#include <hip/hip_runtime.h>
#include <cstdint>

#define CIN    512
#define COUT   32
#define IMH    56
#define IMW    56
#define NB     32
#define CHUNKS 16
#define XSTR   40          // shorts per pixel (32 k + 8 pad) = 80 B
#define NTH    512         // 8 waves: 2x miss concurrency vs R3
#define YT     7           // 8-row output tiles (1.25x halo)
#define SLOTS  2240        // 10 rows x 14 xg x 16 c2
#define SPT    5           // ceil(2240/512)
#define BUFS   (10 * 58 * XSTR)  // 23200 shorts = 46400 B per LDS buffer

typedef __attribute__((ext_vector_type(8))) short v8s;   // 8 bf16 = 4 VGPRs
typedef __attribute__((ext_vector_type(4))) float v4f;

__device__ __forceinline__ unsigned short f2bf(float f) {
    unsigned u = __builtin_bit_cast(unsigned, f);
    u += 0x7FFFu + ((u >> 16) & 1u);          // round-to-nearest-even
    return (unsigned short)(u >> 16);
}

// ---------------------------------------------------------------------------
// Weight transform (fp32 OIHW -> bf16 MFMA A-frag order) + BN const table.
// w2[(((gc*9+tap)*2+mt)*64+lane)*8+j] = W[m=mt*16+(lane&15)][k=gc*32+(lane>>4)*8+j][tap]
// bq[gc*16+c2] = {scale0, shift0, scale1, shift1} for channels gc*32+2*c2, +1
// ---------------------------------------------------------------------------
__global__ void wtransform(const float* __restrict__ cw,
                           const float* __restrict__ bn_w, const float* __restrict__ bn_b,
                           const float* __restrict__ rm,   const float* __restrict__ rv,
                           unsigned short* __restrict__ w2, float4* __restrict__ bq) {
    int idx = blockIdx.x * blockDim.x + threadIdx.x;
    if (idx < 256) {
        int c = idx * 2;
        float s0 = bn_w[c]     * rsqrtf(rv[c]     + 1e-5f);
        float s1 = bn_w[c + 1] * rsqrtf(rv[c + 1] + 1e-5f);
        bq[idx] = make_float4(s0, bn_b[c] - rm[c] * s0, s1, bn_b[c + 1] - rm[c + 1] * s1);
    }
    if (idx >= CHUNKS * 9 * 2 * 64 * 8) return;
    int j    = idx & 7;
    int lane = (idx >> 3) & 63;
    int mt   = (idx >> 9) & 1;
    int tmp  = idx >> 10;
    int tap  = tmp % 9;
    int gc   = tmp / 9;
    int m = mt * 16 + (lane & 15);
    int k = gc * 32 + (lane >> 4) * 8 + j;
    w2[idx] = f2bf(cw[((size_t)m * CIN + k) * 9 + tap]);
}

// ---------------------------------------------------------------------------
// One-pass fused BN+ReLU+3x3 conv, tap-decomposed MFMA implicit GEMM.
// R3 skeleton (224 blocks, 8-row tiles, one barrier/chunk) at 512 threads:
// 8 waves/CU for 2x HBM miss concurrency, all blocks co-resident (no tail).
// Per chunk: weights(gc)->pack(gc)->issue loads(gc+1)->barrier->MFMA(gc).
// ---------------------------------------------------------------------------
struct SlotTab {
    int lbase[SPT];
    int gofs[SPT];
    int actm;            // bit j = slot exists && input row valid
};

__device__ __forceinline__ void load_inputs(const float* __restrict__ p0,
                                            const SlotTab& st,
                                            float4 (&va)[SPT], float4 (&vb)[SPT]) {
    #pragma unroll
    for (int j = 0; j < SPT; ++j) {
        if (st.actm & (1 << j)) {
            const float* p = p0 + st.gofs[j];
            va[j] = *(const float4*)p;
            vb[j] = *(const float4*)(p + 3136);
        }
    }
}

__device__ __forceinline__ void pack_chunk(unsigned short* __restrict__ bp,
                                           const SlotTab& st, float4 bn,
                                           const float4 (&va)[SPT], const float4 (&vb)[SPT]) {
    #pragma unroll
    for (int j = 0; j < SPT; ++j) {
        if (st.actm & (1 << j)) {
            float a0 = fmaxf(fmaf(va[j].x, bn.x, bn.y), 0.f);
            float a1 = fmaxf(fmaf(va[j].y, bn.x, bn.y), 0.f);
            float a2 = fmaxf(fmaf(va[j].z, bn.x, bn.y), 0.f);
            float a3 = fmaxf(fmaf(va[j].w, bn.x, bn.y), 0.f);
            float b0 = fmaxf(fmaf(vb[j].x, bn.z, bn.w), 0.f);
            float b1 = fmaxf(fmaf(vb[j].y, bn.z, bn.w), 0.f);
            float b2 = fmaxf(fmaf(vb[j].z, bn.z, bn.w), 0.f);
            float b3 = fmaxf(fmaf(vb[j].w, bn.z, bn.w), 0.f);
            unsigned u0 = (unsigned)f2bf(a0) | ((unsigned)f2bf(b0) << 16);
            unsigned u1 = (unsigned)f2bf(a1) | ((unsigned)f2bf(b1) << 16);
            unsigned u2 = (unsigned)f2bf(a2) | ((unsigned)f2bf(b2) << 16);
            unsigned u3 = (unsigned)f2bf(a3) | ((unsigned)f2bf(b3) << 16);
            int base = st.lbase[j];
            *(unsigned*)&bp[base]            = u0;
            *(unsigned*)&bp[base + XSTR]     = u1;
            *(unsigned*)&bp[base + 2 * XSTR] = u2;
            *(unsigned*)&bp[base + 3 * XSTR] = u3;
        }
    }
}

__global__ __launch_bounds__(NTH, 1)
void conv_mfma(const float* __restrict__ x,
               const unsigned short* __restrict__ w2,
               const float4* __restrict__ bq,
               float* __restrict__ out)
{
    __shared__ __align__(16) unsigned short s_x[2][BUFS];   // 92800 B

    const int tid  = threadIdx.x;
    const int lane = tid & 63;
    const int wv   = tid >> 6;          // 0..7
    const int yt   = blockIdx.x;        // 0..6
    const int n    = blockIdx.y;        // 0..31
    const int y0   = yt * 8;
    const int c2   = tid & 15;

    // --- slot tables: slot = tid + j*512 -> (c2, xg, row r=0..9) ---
    SlotTab st;
    st.actm = 0;
    #pragma unroll
    for (int j = 0; j < SPT; ++j) {
        int slot = tid + j * NTH;
        bool inr = (slot < SLOTS);
        int rest = slot >> 4;
        int xg = rest % 14;
        int r  = rest / 14;              // 0..9
        int iy = y0 - 1 + r;
        bool v = inr && (iy >= 0) && (iy < IMH);
        if (v) st.actm |= (1 << j);
        st.lbase[j] = (r * 58 + xg * 4 + 1) * XSTR + c2 * 2;
        st.gofs[j]  = c2 * 2 * 3136 + (v ? iy : 0) * 56 + xg * 4;
    }

    // --- prezero halo cols (px 0,57), all 10 rows, both buffers ---
    for (int i = tid; i < 2 * 10 * 2 * 20; i += NTH) {
        int kq = i % 20;
        int t  = i / 20;                 // buf(2) x row(10) x side(2)
        int side = t & 1;
        int r  = (t >> 1) % 10;
        int b  = t / 20;
        *(unsigned*)&s_x[b][(r * 58 + (side ? 57 : 0)) * XSTR + kq * 2] = 0u;
    }
    // --- prezero invalid rows (top/bottom blocks), both buffers; pack skips them ---
    if (yt == 0 || yt == YT - 1) {
        int r = (yt == 0) ? 0 : 9;
        for (int i = tid; i < 2 * 58 * 20; i += NTH) {
            int b = i >= 58 * 20;
            int q = i - b * 58 * 20;
            *(unsigned*)&s_x[b][r * 58 * XSTR + q * 2] = 0u;
        }
    }

    // --- tiles: 28 16-px tiles over 448 px; wave wv owns 4 (wv<4) or 3 ---
    const int ntile = (wv < 4) ? 4 : 3;
    const int tbase = (wv < 4) ? wv * 4 : 16 + (wv - 4) * 3;
    int b_base[4];
    v4f acc[4][2];
    const v4f zero4 = {0.f, 0.f, 0.f, 0.f};
    #pragma unroll
    for (int i = 0; i < 4; ++i) {
        int T  = tbase + ((i < ntile) ? i : 0);
        int p  = T * 16 + (lane & 15);   // 0..447
        int py = p / 56, px = p % 56;    // py 0..7
        b_base[i] = (py * 58 + px) * XSTR + (lane >> 4) * 8;
        acc[i][0] = zero4;
        acc[i][1] = zero4;
    }

    const float* xn = x + (size_t)n * CIN * 3136;

    // --- prologue: inputs for chunk 0 ---
    float4 va[SPT], vb[SPT];
    load_inputs(xn, st, va, vb);

    for (int gc = 0; gc < CHUNKS; ++gc) {
        // weights for chunk gc from L2 (drained at the barrier)
        v8s aw0[9], aw1[9];
        const v8s* wpv = (const v8s*)(w2 + (size_t)gc * 9216);
        #pragma unroll
        for (int t = 0; t < 9; ++t) {
            aw0[t] = wpv[t * 128 + lane];
            aw1[t] = wpv[t * 128 + 64 + lane];
        }

        // pack chunk gc (waits only this chunk's input regs)
        float4 bn = bq[gc * 16 + c2];
        unsigned short* bp = &s_x[gc & 1][0];
        pack_chunk(bp, st, bn, va, vb);

        // issue next chunk's inputs into the now-free register set
        if (gc < CHUNKS - 1)
            load_inputs(xn + (size_t)(gc + 1) * 32 * 3136, st, va, vb);

        __syncthreads();    // drains vmem; LDS visible; WAR-safe via dbuf

        // MFMA chunk gc
        #pragma unroll
        for (int tap = 0; tap < 9; ++tap) {
            const int toff = ((tap / 3) * 58 + (tap % 3)) * XSTR;
            #pragma unroll
            for (int i = 0; i < 4; ++i) {
                if (i < ntile) {
                    v8s b = *(const v8s*)&bp[b_base[i] + toff];
                    acc[i][0] = __builtin_amdgcn_mfma_f32_16x16x32_bf16(aw0[tap], b, acc[i][0], 0, 0, 0);
                    acc[i][1] = __builtin_amdgcn_mfma_f32_16x16x32_bf16(aw1[tap], b, acc[i][1], 0, 0, 0);
                }
            }
        }
    }

    // --- epilogue: direct stores ---
    const int prow = (lane >> 4) * 4;
    #pragma unroll
    for (int i = 0; i < 4; ++i) {
        if (i >= ntile) break;
        int T  = tbase + i;
        int p  = T * 16 + (lane & 15);
        int py = p / 56, px = p % 56;
        size_t o0 = (size_t)n * COUT * 3136 + (size_t)(y0 + py) * 56 + px;
        #pragma unroll
        for (int mt = 0; mt < 2; ++mt) {
            #pragma unroll
            for (int r = 0; r < 4; ++r) {
                int cout = mt * 16 + prow + r;
                out[o0 + (size_t)cout * 3136] = acc[i][mt][r];
            }
        }
    }
}

extern "C" void kernel_launch(void* const* d_in, const int* in_sizes, int n_in,
                              void* d_out, int out_size, void* d_ws, size_t ws_size,
                              hipStream_t stream) {
    const float* x      = (const float*)d_in[0];
    const float* bn_w   = (const float*)d_in[2];
    const float* bn_b   = (const float*)d_in[3];
    const float* r_mean = (const float*)d_in[4];
    const float* r_var  = (const float*)d_in[5];
    const float* cw     = (const float*)d_in[6];
    float* out = (float*)d_out;

    unsigned short* w2 = (unsigned short*)d_ws;                  // 294912 B
    float4* bq = (float4*)((char*)d_ws + 294912);                // 4096 B

    wtransform<<<dim3(576), dim3(256), 0, stream>>>(cw, bn_w, bn_b, r_mean, r_var, w2, bq);

    conv_mfma<<<dim3(YT, NB), dim3(NTH), 0, stream>>>(x, w2, bq, out);
}